// Round 3
// baseline (2443.744 us; speedup 1.0000x reference)
//
#include <hip/hip_runtime.h>
#include <math.h>

// ---------------------------------------------------------------------------
// Swin block, fp32, MI355X. B=32 H=W=56 C=192 NH=6 hd=32 WS=7 SS=3, T=100352.
// Workspace use: ONLY mean/rstd (2 x 401,408 B = 0.8 MB). All large
// intermediates eliminated by fusion; d_out doubles as the attention/x1
// buffer (in-place row-owned GEMMs).
// ---------------------------------------------------------------------------

constexpr long T = 100352;

// ---------------- per-token LayerNorm stats (mean, rstd) -------------------
__global__ __launch_bounds__(256)
void lnstats_k(const float* __restrict__ x, float* __restrict__ mean,
               float* __restrict__ rstd)
{
    const int wave = threadIdx.x >> 6;
    const int lane = threadIdx.x & 63;
    const long tok = (long)blockIdx.x * 4 + wave;
    const float* p = x + tok * 192;
    const float a = p[lane], b = p[lane + 64], c = p[lane + 128];
    float s = a + b + c;
    float q = a * a + b * b + c * c;
    #pragma unroll
    for (int off = 32; off > 0; off >>= 1) {
        s += __shfl_xor(s, off);
        q += __shfl_xor(q, off);
    }
    if (lane == 0) {
        const float m = s * (1.0f / 192.0f);
        const float v = q * (1.0f / 192.0f) - m * m;
        mean[tok] = m;
        rstd[tok] = 1.0f / sqrtf(v + 1e-5f);
    }
}

// ---------------- fused QKV GEMM + windowed attention ----------------------
// One block per (head, window). LDS total 62.1 KB (<64 KB; 2 blocks/CU).
// A = LN1(x) gathered through shift+window (49x192, stored [k][m]).
// qkv-slice GEMM: M=49(pad 64), N=96 (this head's q|k|v cols), K=192.
// Output stored straight to d_out in NATURAL token order (un-shift fused).
__global__ __launch_bounds__(256)
void winattn_k(const float* __restrict__ x, const float* __restrict__ n1g,
               const float* __restrict__ n1b, const float* __restrict__ qkv_w,
               const float* __restrict__ qkv_b, const float* __restrict__ relb,
               const float* __restrict__ mean, const float* __restrict__ rstd,
               float* __restrict__ outp)
{
    __shared__ float As[192 * 52 + 64];   // A^T [k][m], later reused for S
    __shared__ float qs[49 * 32], ks[49 * 32], vs[49 * 32];
    __shared__ float Bs[8 * 96];
    const int head = blockIdx.x;          // 0..5
    const int bw   = blockIdx.y;          // 0..2047
    const int tid  = threadIdx.x;
    const int b = bw >> 6, wi = bw & 63, wh = wi >> 3, ww = wi & 7;

    // Phase A: LN1 + shift + window gather -> As[k][m]
    for (int idx = tid; idx < 2352; idx += 256) {        // 49 rows x 48 float4
        const int n = idx / 48, q4 = idx - n * 48;
        const int yi = n / 7, xi = n - yi * 7;
        int h = wh * 7 + yi + 3; if (h >= 56) h -= 56;
        int w = ww * 7 + xi + 3; if (w >= 56) w -= 56;
        const long tok = (long)b * 3136 + h * 56 + w;
        const float4 v  = *(const float4*)(x + tok * 192 + q4 * 4);
        const float m_ = mean[tok], rs_ = rstd[tok];
        const float4 g  = *(const float4*)(n1g + q4 * 4);
        const float4 be = *(const float4*)(n1b + q4 * 4);
        As[(q4 * 4 + 0) * 52 + n] = (v.x - m_) * rs_ * g.x + be.x;
        As[(q4 * 4 + 1) * 52 + n] = (v.y - m_) * rs_ * g.y + be.y;
        As[(q4 * 4 + 2) * 52 + n] = (v.z - m_) * rs_ * g.z + be.z;
        As[(q4 * 4 + 3) * 52 + n] = (v.w - m_) * rs_ * g.w + be.w;
    }

    // Phase B: qkv GEMM for this head's 96 W-columns (3 strips of 32)
    const int tx = tid & 15, ty = tid >> 4;
    float acc[4][6] = {};
    for (int k0 = 0; k0 < 192; k0 += 8) {
        __syncthreads();
        if (tid < 192) {
            const int kr = tid / 24, c4 = tid - kr * 24;
            const int s = c4 >> 3, off = (c4 & 7) << 2;
            *(float4*)&Bs[kr * 96 + c4 * 4] =
                *(const float4*)(qkv_w + (long)(k0 + kr) * 576 + s * 192 + head * 32 + off);
        }
        __syncthreads();
        #pragma unroll
        for (int kk = 0; kk < 8; ++kk) {
            const float4 a = *(const float4*)&As[(k0 + kk) * 52 + (ty << 2)];
            const float* bp = &Bs[kk * 96 + tx * 6];
            #pragma unroll
            for (int c = 0; c < 6; ++c) {
                const float bv = bp[c];
                acc[0][c] += a.x * bv;
                acc[1][c] += a.y * bv;
                acc[2][c] += a.z * bv;
                acc[3][c] += a.w * bv;
            }
        }
    }
    __syncthreads();

    // Phase C: scatter to qs/ks/vs (+bias, q pre-scaled)
    const float scale = 0.17677669529663687f;   // 32^-0.5
    #pragma unroll
    for (int r = 0; r < 4; ++r) {
        const int m = (ty << 2) + r;
        if (m < 49) {
            #pragma unroll
            for (int c = 0; c < 6; ++c) {
                const int n = tx * 6 + c, s = n >> 5, d = n & 31;
                const float val = acc[r][c] + qkv_b[s * 192 + head * 32 + d];
                if (s == 0)      qs[m * 32 + d] = val * scale;
                else if (s == 1) ks[m * 32 + d] = val;
                else             vs[m * 32 + d] = val;
            }
        }
    }
    __syncthreads();

    // Phase D: S = q k^T + rel-bias + shift-mask   (S overlays As)
    float* S = As;
    for (int e = tid; e < 2401; e += 256) {
        const int i = e / 49, j = e - i * 49;
        float s = 0.f;
        #pragma unroll
        for (int t = 0; t < 8; ++t) {
            const float4 a  = *(const float4*)&qs[i * 32 + (t << 2)];
            const float4 b2 = *(const float4*)&ks[j * 32 + (t << 2)];
            s += a.x * b2.x + a.y * b2.y + a.z * b2.z + a.w * b2.w;
        }
        const int yi = i / 7, xi = i - yi * 7;
        const int yj = j / 7, xj = j - yj * 7;
        s += relb[((yi - yj + 6) * 13 + (xi - xj + 6)) * 6 + head];
        const int hi = wh * 7 + yi, hj = wh * 7 + yj;
        const int wa = ww * 7 + xi, wb = ww * 7 + xj;
        const int Li = (hi < 49 ? 0 : (hi < 53 ? 1 : 2)) * 3 + (wa < 49 ? 0 : (wa < 53 ? 1 : 2));
        const int Lj = (hj < 49 ? 0 : (hj < 53 ? 1 : 2)) * 3 + (wb < 49 ? 0 : (wb < 53 ? 1 : 2));
        S[i * 50 + j] = (Li != Lj) ? s - 100.0f : s;
    }
    __syncthreads();

    if (tid < 49) {                                // softmax, row per thread
        float mx = -1e30f;
        for (int j = 0; j < 49; ++j) mx = fmaxf(mx, S[tid * 50 + j]);
        float sum = 0.f;
        for (int j = 0; j < 49; ++j) {
            const float e = expf(S[tid * 50 + j] - mx);
            S[tid * 50 + j] = e; sum += e;
        }
        const float inv = 1.0f / sum;
        for (int j = 0; j < 49; ++j) S[tid * 50 + j] *= inv;
    }
    __syncthreads();

    // Phase E: O = S @ V, store to d_out natural order (un-shift fused)
    for (int e = tid; e < 1568; e += 256) {
        const int i = e >> 5, d = e & 31;
        float o = 0.f;
        for (int j = 0; j < 49; ++j) o += S[i * 50 + j] * vs[j * 32 + d];
        const int yi = i / 7, xi = i - yi * 7;
        int h = wh * 7 + yi + 3; if (h >= 56) h -= 56;
        int w = ww * 7 + xi + 3; if (w >= 56) w -= 56;
        outp[((long)b * 3136 + h * 56 + w) * 192 + head * 32 + d] = o;
    }
}

// ---------------- in-place proj GEMM + residual ----------------------------
// Block owns 64 rows of d_out: reads them fully into LDS first, computes the
// whole 192-wide output row-block, writes back. attnb == outp (in place) --
// no __restrict__ on those.
__global__ __launch_bounds__(256)
void proj_k(const float* attnb, const float* __restrict__ pw,
            const float* __restrict__ pb, const float* __restrict__ x,
            float* outp)
{
    __shared__ float An[192 * 64];     // A^T [k][m]
    __shared__ float Cs[8 * 192];
    const int tid = threadIdx.x;
    const long m0 = (long)blockIdx.x * 64;

    for (int idx = tid; idx < 3072; idx += 256) {       // 64 rows x 48 float4
        const int r = idx / 48, q4 = idx - r * 48;
        const float4 v = *(const float4*)(attnb + (m0 + r) * 192 + q4 * 4);
        An[(q4 * 4 + 0) * 64 + r] = v.x;
        An[(q4 * 4 + 1) * 64 + r] = v.y;
        An[(q4 * 4 + 2) * 64 + r] = v.z;
        An[(q4 * 4 + 3) * 64 + r] = v.w;
    }
    const int tx = tid & 15, ty = tid >> 4;
    float acc[4][12] = {};
    for (int k0 = 0; k0 < 192; k0 += 8) {
        __syncthreads();
        for (int idx = tid; idx < 384; idx += 256) {
            const int rr = idx / 48, c4 = idx - rr * 48;
            *(float4*)&Cs[rr * 192 + c4 * 4] =
                *(const float4*)(pw + (long)(k0 + rr) * 192 + c4 * 4);
        }
        __syncthreads();
        #pragma unroll
        for (int kk = 0; kk < 8; ++kk) {
            const float4 a  = *(const float4*)&An[(k0 + kk) * 64 + (ty << 2)];
            const float4 b0 = *(const float4*)&Cs[kk * 192 + tx * 12];
            const float4 b1 = *(const float4*)&Cs[kk * 192 + tx * 12 + 4];
            const float4 b2 = *(const float4*)&Cs[kk * 192 + tx * 12 + 8];
            #pragma unroll
            for (int r = 0; r < 4; ++r) {
                const float ar = (r == 0) ? a.x : (r == 1) ? a.y : (r == 2) ? a.z : a.w;
                acc[r][0] += ar * b0.x; acc[r][1]  += ar * b0.y;
                acc[r][2] += ar * b0.z; acc[r][3]  += ar * b0.w;
                acc[r][4] += ar * b1.x; acc[r][5]  += ar * b1.y;
                acc[r][6] += ar * b1.z; acc[r][7]  += ar * b1.w;
                acc[r][8] += ar * b2.x; acc[r][9]  += ar * b2.y;
                acc[r][10] += ar * b2.z; acc[r][11] += ar * b2.w;
            }
        }
    }
    #pragma unroll
    for (int r = 0; r < 4; ++r) {
        const long row = m0 + (ty << 2) + r;
        #pragma unroll
        for (int c = 0; c < 3; ++c) {
            const int col = tx * 12 + (c << 2);
            const float4 pbv = *(const float4*)(pb + col);
            const float4 xv  = *(const float4*)(x + row * 192 + col);
            float4 o;
            o.x = acc[r][c * 4 + 0] + pbv.x + xv.x;
            o.y = acc[r][c * 4 + 1] + pbv.y + xv.y;
            o.z = acc[r][c * 4 + 2] + pbv.z + xv.z;
            o.w = acc[r][c * 4 + 3] + pbv.w + xv.w;
            *(float4*)(outp + row * 192 + col) = o;
        }
    }
}

// ---------------- fused MLP: out = x1 + GELU(LN2(x1)@fc1+b1)@fc2 + b2 ------
// Block owns 32 rows (in place on d_out). LN2(x1)^T kept in LDS across all
// 12 hid-tiles; htile round-trips through LDS transposed for the fc2 GEMM.
__global__ __launch_bounds__(256)
void mlp_k(const float* x1, const float* __restrict__ n2g,
           const float* __restrict__ n2b, const float* __restrict__ w1,
           const float* __restrict__ b1, const float* __restrict__ w2,
           const float* __restrict__ b2, const float* __restrict__ mean,
           const float* __restrict__ rstd, float* outp)
{
    __shared__ float An[192 * 32];     // LN2(x1)^T [k][m]
    __shared__ float Hs[64 * 34];      // htile^T [hid][m], stride 34
    __shared__ float Bs[16 * 64];      // fc1 chunk
    __shared__ float Cs[8 * 192];      // fc2 chunk
    const int tid = threadIdx.x;
    const long m0 = (long)blockIdx.x * 32;

    for (int idx = tid; idx < 1536; idx += 256) {       // 32 rows x 48 float4
        const int r = idx / 48, q4 = idx - r * 48;
        const long tok = m0 + r;
        const float4 v = *(const float4*)(x1 + tok * 192 + q4 * 4);
        const float m_ = mean[tok], rs_ = rstd[tok];
        const float4 g  = *(const float4*)(n2g + q4 * 4);
        const float4 be = *(const float4*)(n2b + q4 * 4);
        An[(q4 * 4 + 0) * 32 + r] = (v.x - m_) * rs_ * g.x + be.x;
        An[(q4 * 4 + 1) * 32 + r] = (v.y - m_) * rs_ * g.y + be.y;
        An[(q4 * 4 + 2) * 32 + r] = (v.z - m_) * rs_ * g.z + be.z;
        An[(q4 * 4 + 3) * 32 + r] = (v.w - m_) * rs_ * g.w + be.w;
    }

    const int tx = tid & 15, ty = tid >> 4;
    float accO[2][12] = {};
    for (int t = 0; t < 12; ++t) {
        // GEMM1: htile(32x64) = An^T @ fc1[:, t*64..]
        float accH[2][4] = {};
        for (int k0 = 0; k0 < 192; k0 += 16) {
            __syncthreads();
            *(float4*)&Bs[(tid >> 4) * 64 + ((tid & 15) << 2)] =
                *(const float4*)(w1 + (long)(k0 + (tid >> 4)) * 768 + t * 64 + ((tid & 15) << 2));
            __syncthreads();
            #pragma unroll
            for (int kk = 0; kk < 16; ++kk) {
                const float2 a  = *(const float2*)&An[(k0 + kk) * 32 + (ty << 1)];
                const float4 bv = *(const float4*)&Bs[kk * 64 + (tx << 2)];
                accH[0][0] += a.x * bv.x; accH[0][1] += a.x * bv.y;
                accH[0][2] += a.x * bv.z; accH[0][3] += a.x * bv.w;
                accH[1][0] += a.y * bv.x; accH[1][1] += a.y * bv.y;
                accH[1][2] += a.y * bv.z; accH[1][3] += a.y * bv.w;
            }
        }
        __syncthreads();
        #pragma unroll
        for (int r = 0; r < 2; ++r)
            #pragma unroll
            for (int c = 0; c < 4; ++c) {
                float val = accH[r][c] + b1[t * 64 + (tx << 2) + c];
                val = 0.5f * val * (1.0f + erff(val * 0.7071067811865476f));
                Hs[((tx << 2) + c) * 34 + (ty << 1) + r] = val;
            }
        __syncthreads();
        // GEMM2: accO += htile @ fc2[t*64.., :]
        for (int h0 = 0; h0 < 64; h0 += 8) {
            __syncthreads();
            for (int idx = tid; idx < 384; idx += 256) {
                const int rr = idx / 48, c4 = idx - rr * 48;
                *(float4*)&Cs[rr * 192 + c4 * 4] =
                    *(const float4*)(w2 + (long)(t * 64 + h0 + rr) * 192 + c4 * 4);
            }
            __syncthreads();
            #pragma unroll
            for (int kk = 0; kk < 8; ++kk) {
                const float2 a   = *(const float2*)&Hs[(h0 + kk) * 34 + (ty << 1)];
                const float4 c0v = *(const float4*)&Cs[kk * 192 + tx * 12];
                const float4 c1v = *(const float4*)&Cs[kk * 192 + tx * 12 + 4];
                const float4 c2v = *(const float4*)&Cs[kk * 192 + tx * 12 + 8];
                #pragma unroll
                for (int r = 0; r < 2; ++r) {
                    const float ar = (r == 0) ? a.x : a.y;
                    accO[r][0] += ar * c0v.x; accO[r][1]  += ar * c0v.y;
                    accO[r][2] += ar * c0v.z; accO[r][3]  += ar * c0v.w;
                    accO[r][4] += ar * c1v.x; accO[r][5]  += ar * c1v.y;
                    accO[r][6] += ar * c1v.z; accO[r][7]  += ar * c1v.w;
                    accO[r][8] += ar * c2v.x; accO[r][9]  += ar * c2v.y;
                    accO[r][10] += ar * c2v.z; accO[r][11] += ar * c2v.w;
                }
            }
        }
    }
    #pragma unroll
    for (int r = 0; r < 2; ++r) {
        const long row = m0 + (ty << 1) + r;
        #pragma unroll
        for (int c = 0; c < 3; ++c) {
            const int col = tx * 12 + (c << 2);
            const float4 xv = *(const float4*)(x1 + row * 192 + col);
            const float4 bv = *(const float4*)(b2 + col);
            float4 o;
            o.x = accO[r][c * 4 + 0] + bv.x + xv.x;
            o.y = accO[r][c * 4 + 1] + bv.y + xv.y;
            o.z = accO[r][c * 4 + 2] + bv.z + xv.z;
            o.w = accO[r][c * 4 + 3] + bv.w + xv.w;
            *(float4*)(outp + row * 192 + col) = o;
        }
    }
}

// ---------------------------------------------------------------------------
extern "C" void kernel_launch(void* const* d_in, const int* in_sizes, int n_in,
                              void* d_out, int out_size, void* d_ws, size_t ws_size,
                              hipStream_t stream)
{
    const float* x      = (const float*)d_in[0];
    const float* n1g    = (const float*)d_in[1];
    const float* n1b    = (const float*)d_in[2];
    const float* qkv_w  = (const float*)d_in[3];
    const float* qkv_b  = (const float*)d_in[4];
    const float* relb   = (const float*)d_in[5];
    const float* proj_w = (const float*)d_in[6];
    const float* proj_b = (const float*)d_in[7];
    const float* n2g    = (const float*)d_in[8];
    const float* n2b    = (const float*)d_in[9];
    const float* fc1_w  = (const float*)d_in[10];
    const float* fc1_b  = (const float*)d_in[11];
    const float* fc2_w  = (const float*)d_in[12];
    const float* fc2_b  = (const float*)d_in[13];
    float* out = (float*)d_out;
    char*  ws  = (char*)d_ws;

    float* mb = (float*)(ws);            // 401,408 B
    float* rb = (float*)(ws + 401408L);  // 401,408 B   (total ws use: 0.8 MB)

    // 1) LN1 stats on x
    lnstats_k<<<T / 4, 256, 0, stream>>>(x, mb, rb);
    // 2) fused LN1+shift+window+QKV+attention -> d_out (natural token order)
    winattn_k<<<dim3(6, 2048), 256, 0, stream>>>(x, n1g, n1b, qkv_w, qkv_b,
                                                 relb, mb, rb, out);
    // 3) x1 = attn @ proj_w + proj_b + x   (in place on d_out)
    proj_k<<<T / 64, 256, 0, stream>>>(out, proj_w, proj_b, x, out);
    // 4) LN2 stats on x1
    lnstats_k<<<T / 4, 256, 0, stream>>>(out, mb, rb);
    // 5) out = x1 + GELU(LN2(x1)@fc1+b1)@fc2 + b2   (in place on d_out)
    mlp_k<<<T / 32, 256, 0, stream>>>(out, n2g, n2b, fc1_w, fc1_b,
                                      fc2_w, fc2_b, mb, rb, out);
}

// Round 4
// 1061.939 us; speedup vs baseline: 2.3012x; 2.3012x over previous
//
#include <hip/hip_runtime.h>
#include <math.h>

// ---------------------------------------------------------------------------
// Swin block, bf16-MFMA, MI355X. B=32 H=W=56 C=192 NH=6 hd=32 WS=7 SS=3.
// T=100352. GEMMs: 16x16x32 bf16 MFMA, fp32 accum. LN/softmax/GELU/residual
// in fp32. Weights repacked per-launch into MFMA B-fragment order (bf16) in
// ws; B-frags load straight global->VGPR (16B/lane coalesced, L2-resident).
// ws use: mean/rstd 0.8MB + packs 0.87MB + bias/mask table 0.23MB = 1.9MB.
// ---------------------------------------------------------------------------

constexpr long T = 100352;

typedef __attribute__((ext_vector_type(8))) short short8;   // 8 bf16
typedef __attribute__((ext_vector_type(4))) float f32x4;    // MFMA acc

__device__ __forceinline__ short bf16(float f) {
    union { float f; unsigned u; } v; v.f = f;
    return (short)((v.u + 0x7fff + ((v.u >> 16) & 1)) >> 16);
}

// B-fragment pack: element (k,n) of a KxN row-major weight ->
// flat = ((ntile*Kst + kstep)*64 + lane)*8 + k%8, lane = (n&15) + 16*((k>>3)&3)
template<int K, int N>
__global__ __launch_bounds__(256)
void pack_k(const float* __restrict__ W, short* __restrict__ P)
{
    const int idx = blockIdx.x * 256 + threadIdx.x;   // = k*N + n
    const int k = idx / N, n = idx - k * N;
    constexpr int Kst = K / 32;
    const int flat = (((n >> 4) * Kst + (k >> 5)) * 64 +
                      (((k >> 3) & 3) << 4) + (n & 15)) * 8 + (k & 7);
    P[flat] = bf16(W[idx]);
}

// combined rel-pos-bias + shift-mask table: [head][th][tw][i*49+j]
// th/tw = 1 iff window is the last one (wh==7 / ww==7)
__global__ __launch_bounds__(256)
void biasprep_k(const float* __restrict__ relb, float* __restrict__ bm)
{
    const int idx = blockIdx.x * 256 + threadIdx.x;
    if (idx >= 6 * 4 * 2401) return;
    const int e = idx % 2401, rest = idx / 2401;
    const int tw = rest & 1, th = (rest >> 1) & 1, head = rest >> 2;
    const int i = e / 49, j = e - i * 49;
    const int yi = i / 7, xi = i - yi * 7, yj = j / 7, xj = j - yj * 7;
    const float v = relb[((yi - yj + 6) * 13 + (xi - xj + 6)) * 6 + head];
    const int hi = th ? 49 + yi : yi, hj = th ? 49 + yj : yj;
    const int wa = tw ? 49 + xi : xi, wb = tw ? 49 + xj : xj;
    const int Li = (hi < 49 ? 0 : (hi < 53 ? 1 : 2)) * 3 + (wa < 49 ? 0 : (wa < 53 ? 1 : 2));
    const int Lj = (hj < 49 ? 0 : (hj < 53 ? 1 : 2)) * 3 + (wb < 49 ? 0 : (wb < 53 ? 1 : 2));
    bm[idx] = (Li != Lj) ? v - 100.0f : v;
}

// ---------------- per-token LayerNorm stats (mean, rstd) — LN1 only --------
__global__ __launch_bounds__(256)
void lnstats_k(const float* __restrict__ x, float* __restrict__ mean,
               float* __restrict__ rstd)
{
    const int wave = threadIdx.x >> 6;
    const int lane = threadIdx.x & 63;
    const long tok = (long)blockIdx.x * 4 + wave;
    const float* p = x + tok * 192;
    const float a = p[lane], b = p[lane + 64], c = p[lane + 128];
    float s = a + b + c;
    float q = a * a + b * b + c * c;
    #pragma unroll
    for (int off = 32; off > 0; off >>= 1) {
        s += __shfl_xor(s, off);
        q += __shfl_xor(q, off);
    }
    if (lane == 0) {
        const float m = s * (1.0f / 192.0f);
        const float v = q * (1.0f / 192.0f) - m * m;
        mean[tok] = m;
        rstd[tok] = 1.0f / sqrtf(v + 1e-5f);
    }
}

// ---------------- fused LN1+shift+window+QKV(MFMA)+attention ---------------
// block = (head, window). A = LN1 gather 49(pad 64)x192 bf16 in frag layout;
// per wave: mtile=wave, 6 ntiles x 6 ksteps = 36 MFMAs. Attention fp32.
__global__ __launch_bounds__(256)
void winattn_k(const float* __restrict__ x, const float* __restrict__ n1g,
               const float* __restrict__ n1b, const short* __restrict__ qkvP,
               const float* __restrict__ qkv_b, const float* __restrict__ bm,
               const float* __restrict__ mean, const float* __restrict__ rstd,
               float* __restrict__ outp)
{
    __shared__ __align__(16) short As[12288];   // A-pack; reused as S (f32)
    __shared__ __align__(16) float qs[49 * 32], ks_[49 * 32], vs[49 * 32];
    const int head = blockIdx.x;   // 0..5
    const int bw   = blockIdx.y;   // 0..2047
    const int tid  = threadIdx.x;
    const int b = bw >> 6, wi = bw & 63, wh = wi >> 3, ww = wi & 7;
    const int wave = tid >> 6, lane = tid & 63;

    // zero pad rows (m 49..63 garbage-proofing), then LN1 gather into A-pack
    for (int i = tid; i < 6144; i += 256) ((int*)As)[i] = 0;
    __syncthreads();
    for (int idx = tid; idx < 2352; idx += 256) {   // 49 tokens x 48 float4
        const int m = idx / 48, q4 = idx - m * 48, k0 = q4 * 4;
        const int yi = m / 7, xi = m - yi * 7;
        int h = wh * 7 + yi + 3; if (h >= 56) h -= 56;
        int w = ww * 7 + xi + 3; if (w >= 56) w -= 56;
        const long tok = (long)b * 3136 + h * 56 + w;
        const float4 v  = *(const float4*)(x + tok * 192 + k0);
        const float m_ = mean[tok], rs_ = rstd[tok];
        const float4 g  = *(const float4*)(n1g + k0);
        const float4 be = *(const float4*)(n1b + k0);
        const short4 s4 = make_short4(
            bf16((v.x - m_) * rs_ * g.x + be.x), bf16((v.y - m_) * rs_ * g.y + be.y),
            bf16((v.z - m_) * rs_ * g.z + be.z), bf16((v.w - m_) * rs_ * g.w + be.w));
        const int flat = (((m >> 4) * 6 + (k0 >> 5)) * 64 +
                          (((k0 >> 3) & 3) << 4) + (m & 15)) * 8 + (k0 & 7);
        *(short4*)&As[flat] = s4;
    }
    __syncthreads();

    // QKV slice GEMM: M=64 x N=96 x K=192
    f32x4 acc[6] = {};
    for (int ks = 0; ks < 6; ++ks) {
        const short8 a = *(const short8*)&As[((wave * 6 + ks) << 9) + (lane << 3)];
        #pragma unroll
        for (int nt = 0; nt < 6; ++nt) {
            const int ntg = (nt >> 1) * 12 + head * 2 + (nt & 1);
            const short8 bfr = *(const short8*)(qkvP + ((ntg * 6 + ks) * 64 + lane) * 8);
            acc[nt] = __builtin_amdgcn_mfma_f32_16x16x32_bf16(a, bfr, acc[nt], 0, 0, 0);
        }
    }

    // scatter C to qs/ks/vs (+bias, q prescaled)
    const float scale = 0.17677669529663687f;   // 32^-0.5
    const int col = lane & 15, rbase = (lane >> 4) << 2;
    #pragma unroll
    for (int nt = 0; nt < 6; ++nt) {
        const int s = nt >> 1, d = ((nt & 1) << 4) + col;
        const float bias = qkv_b[s * 192 + head * 32 + d];
        #pragma unroll
        for (int r = 0; r < 4; ++r) {
            const int m = (wave << 4) + rbase + r;
            if (m < 49) {
                const float val = acc[nt][r] + bias;
                if (s == 0)      qs[m * 32 + d] = val * scale;
                else if (s == 1) ks_[m * 32 + d] = val;
                else             vs[m * 32 + d] = val;
            }
        }
    }
    __syncthreads();

    // S = q k^T + bias/mask table   (S overlays As)
    float* S = (float*)As;
    const float* bmp = bm + (((head << 1) + (wh == 7)) * 2 + (ww == 7)) * 2401;
    for (int e = tid; e < 2401; e += 256) {
        const int i = e / 49, j = e - i * 49;
        float s = 0.f;
        #pragma unroll
        for (int t = 0; t < 8; ++t) {
            const float4 a  = *(const float4*)&qs[i * 32 + (t << 2)];
            const float4 b2 = *(const float4*)&ks_[j * 32 + (t << 2)];
            s += a.x * b2.x + a.y * b2.y + a.z * b2.z + a.w * b2.w;
        }
        S[i * 50 + j] = s + bmp[e];
    }
    __syncthreads();

    if (tid < 49) {                 // softmax, row per thread
        float mx = -1e30f;
        for (int j = 0; j < 49; ++j) mx = fmaxf(mx, S[tid * 50 + j]);
        float sum = 0.f;
        for (int j = 0; j < 49; ++j) {
            const float e = __expf(S[tid * 50 + j] - mx);
            S[tid * 50 + j] = e; sum += e;
        }
        const float inv = 1.0f / sum;
        for (int j = 0; j < 49; ++j) S[tid * 50 + j] *= inv;
    }
    __syncthreads();

    // O = S @ V, store natural token order (un-shift fused)
    for (int e = tid; e < 1568; e += 256) {
        const int i = e >> 5, d = e & 31;
        float o = 0.f;
        for (int j = 0; j < 49; ++j) o += S[i * 50 + j] * vs[j * 32 + d];
        const int yi = i / 7, xi = i - yi * 7;
        int h = wh * 7 + yi + 3; if (h >= 56) h -= 56;
        int w = ww * 7 + xi + 3; if (w >= 56) w -= 56;
        outp[((long)b * 3136 + h * 56 + w) * 192 + head * 32 + d] = o;
    }
}

// ---------------- proj GEMM (MFMA) + residual, in place on d_out -----------
__global__ __launch_bounds__(256)
void proj_k(const float* attnb, const short* __restrict__ projP,
            const float* __restrict__ pb, const float* __restrict__ x,
            float* outp)
{
    __shared__ __align__(16) short As[12288];   // 64x192 A-pack
    const int tid = threadIdx.x;
    const int wave = tid >> 6, lane = tid & 63;
    const long m0 = (long)blockIdx.x * 64;

    for (int idx = tid; idx < 3072; idx += 256) {   // 64 rows x 48 float4
        const int m = idx / 48, q4 = idx - m * 48, k0 = q4 * 4;
        const float4 v = *(const float4*)(attnb + (m0 + m) * 192 + k0);
        const short4 s4 = make_short4(bf16(v.x), bf16(v.y), bf16(v.z), bf16(v.w));
        const int flat = (((m >> 4) * 6 + (k0 >> 5)) * 64 +
                          (((k0 >> 3) & 3) << 4) + (m & 15)) * 8 + (k0 & 7);
        *(short4*)&As[flat] = s4;
    }
    __syncthreads();

    f32x4 acc[12] = {};
    for (int ks = 0; ks < 6; ++ks) {
        const short8 a = *(const short8*)&As[((wave * 6 + ks) << 9) + (lane << 3)];
        #pragma unroll
        for (int nt = 0; nt < 12; ++nt) {
            const short8 bfr = *(const short8*)(projP + ((nt * 6 + ks) * 64 + lane) * 8);
            acc[nt] = __builtin_amdgcn_mfma_f32_16x16x32_bf16(a, bfr, acc[nt], 0, 0, 0);
        }
    }

    const int col = lane & 15, rbase = (lane >> 4) << 2;
    #pragma unroll
    for (int nt = 0; nt < 12; ++nt) {
        const int n = (nt << 4) + col;
        const float bias = pb[n];
        #pragma unroll
        for (int r = 0; r < 4; ++r) {
            const long row = m0 + (wave << 4) + rbase + r;
            outp[row * 192 + n] = acc[nt][r] + bias + x[row * 192 + n];
        }
    }
}

// ---------------- fused MLP (MFMA): out = x1 + GELU(LN2(x1)@W1+b1)@W2+b2 ---
// block owns 64 rows (in place). LN2 stats computed in-kernel (4 thr/row).
// H tile (64x64) is wave-private in LDS -> no barriers in the t-loop.
__global__ __launch_bounds__(256)
void mlp_k(const float* x1, const float* __restrict__ n2g,
           const float* __restrict__ n2b, const short* __restrict__ fc1P,
           const float* __restrict__ b1, const short* __restrict__ fc2P,
           const float* __restrict__ b2, float* outp)
{
    __shared__ __align__(16) short As[12288];   // LN2(x1) 64x192 A-pack
    __shared__ __align__(16) short Hs[4096];    // H 64x64 A-pack (per-wave mtile)
    const int tid = threadIdx.x;
    const int wave = tid >> 6, lane = tid & 63;
    const long m0 = (long)blockIdx.x * 64;

    // LN2 stats + pack: 4 threads per row
    {
        const int row = tid >> 2, seg = tid & 3;
        const float* xp = x1 + (m0 + row) * 192;
        float s = 0.f, q = 0.f;
        #pragma unroll
        for (int c = 0; c < 12; ++c) {
            const float4 v = *(const float4*)(xp + ((c << 2) + seg) * 4);
            s += v.x + v.y + v.z + v.w;
            q += v.x * v.x + v.y * v.y + v.z * v.z + v.w * v.w;
        }
        s += __shfl_xor(s, 1); s += __shfl_xor(s, 2);
        q += __shfl_xor(q, 1); q += __shfl_xor(q, 2);
        const float m_ = s * (1.0f / 192.0f);
        const float rs_ = rsqrtf(q * (1.0f / 192.0f) - m_ * m_ + 1e-5f);
        const int mt = row >> 4, ml = row & 15;
        #pragma unroll
        for (int c = 0; c < 12; ++c) {
            const int k0 = ((c << 2) + seg) * 4;
            const float4 v  = *(const float4*)(xp + k0);
            const float4 g  = *(const float4*)(n2g + k0);
            const float4 be = *(const float4*)(n2b + k0);
            const short4 s4 = make_short4(
                bf16((v.x - m_) * rs_ * g.x + be.x), bf16((v.y - m_) * rs_ * g.y + be.y),
                bf16((v.z - m_) * rs_ * g.z + be.z), bf16((v.w - m_) * rs_ * g.w + be.w));
            const int flat = ((mt * 6 + (k0 >> 5)) * 64 +
                              (((k0 >> 3) & 3) << 4) + ml) * 8 + (k0 & 7);
            *(short4*)&As[flat] = s4;
        }
    }
    __syncthreads();

    const int col = lane & 15, rbase = (lane >> 4) << 2;
    f32x4 accO[12] = {};
    for (int t = 0; t < 12; ++t) {
        // GEMM1: H = A(64x192) @ W1[:, t*64..+64)
        f32x4 accH[4] = {};
        for (int ks = 0; ks < 6; ++ks) {
            const short8 a = *(const short8*)&As[((wave * 6 + ks) << 9) + (lane << 3)];
            #pragma unroll
            for (int nt = 0; nt < 4; ++nt) {
                const short8 bfr = *(const short8*)(fc1P + ((((t << 2) + nt) * 6 + ks) * 64 + lane) * 8);
                accH[nt] = __builtin_amdgcn_mfma_f32_16x16x32_bf16(a, bfr, accH[nt], 0, 0, 0);
            }
        }
        // bias + exact GELU -> repack into Hs (wave-private region)
        #pragma unroll
        for (int nt = 0; nt < 4; ++nt) {
            const int kh = (nt << 4) + col;          // local hid 0..63
            const float bias = b1[(t << 6) + kh];
            #pragma unroll
            for (int r = 0; r < 4; ++r) {
                const int m = (wave << 4) + rbase + r;
                float val = accH[nt][r] + bias;
                val = 0.5f * val * (1.0f + erff(val * 0.7071067811865476f));
                const int flat = (((wave << 1) + (kh >> 5)) * 64 +
                                  (((kh >> 3) & 3) << 4) + (m & 15)) * 8 + (kh & 7);
                Hs[flat] = bf16(val);
            }
        }
        // GEMM2: accO += H(64x64) @ W2[t*64..+64, :]
        #pragma unroll
        for (int ks = 0; ks < 2; ++ks) {
            const short8 a = *(const short8*)&Hs[(((wave << 1) + ks) << 9) + (lane << 3)];
            #pragma unroll
            for (int nt = 0; nt < 12; ++nt) {
                const short8 bfr = *(const short8*)(fc2P + ((nt * 24 + (t << 1) + ks) * 64 + lane) * 8);
                accO[nt] = __builtin_amdgcn_mfma_f32_16x16x32_bf16(a, bfr, accO[nt], 0, 0, 0);
            }
        }
    }

    #pragma unroll
    for (int nt = 0; nt < 12; ++nt) {
        const int n = (nt << 4) + col;
        const float bias = b2[n];
        #pragma unroll
        for (int r = 0; r < 4; ++r) {
            const long row = m0 + (wave << 4) + rbase + r;
            outp[row * 192 + n] = accO[nt][r] + bias + x1[row * 192 + n];
        }
    }
}

// ---------------------------------------------------------------------------
extern "C" void kernel_launch(void* const* d_in, const int* in_sizes, int n_in,
                              void* d_out, int out_size, void* d_ws, size_t ws_size,
                              hipStream_t stream)
{
    const float* x      = (const float*)d_in[0];
    const float* n1g    = (const float*)d_in[1];
    const float* n1b    = (const float*)d_in[2];
    const float* qkv_w  = (const float*)d_in[3];
    const float* qkv_b  = (const float*)d_in[4];
    const float* relb   = (const float*)d_in[5];
    const float* proj_w = (const float*)d_in[6];
    const float* proj_b = (const float*)d_in[7];
    const float* n2g    = (const float*)d_in[8];
    const float* n2b    = (const float*)d_in[9];
    const float* fc1_w  = (const float*)d_in[10];
    const float* fc1_b  = (const float*)d_in[11];
    const float* fc2_w  = (const float*)d_in[12];
    const float* fc2_b  = (const float*)d_in[13];
    float* out = (float*)d_out;
    char*  ws  = (char*)d_ws;

    float* mb    = (float*)(ws);                   //   401,408 B
    float* rb    = (float*)(ws +   401408L);       //   401,408 B
    short* qkvP  = (short*)(ws +   802816L);       //   221,184 B
    short* projP = (short*)(ws +  1024000L);       //    73,728 B
    short* fc1P  = (short*)(ws +  1097728L);       //   294,912 B
    short* fc2P  = (short*)(ws +  1392640L);       //   294,912 B
    float* bmT   = (float*)(ws +  1687552L);       //   230,496 B  (~1.92 MB total)

    // weight repacks + bias/mask table (tiny; run every launch)
    pack_k<192, 576><<<432, 256, 0, stream>>>(qkv_w, qkvP);
    pack_k<192, 192><<<144, 256, 0, stream>>>(proj_w, projP);
    pack_k<192, 768><<<576, 256, 0, stream>>>(fc1_w, fc1P);
    pack_k<768, 192><<<576, 256, 0, stream>>>(fc2_w, fc2P);
    biasprep_k<<<226, 256, 0, stream>>>(relb, bmT);

    // 1) LN1 stats
    lnstats_k<<<T / 4, 256, 0, stream>>>(x, mb, rb);
    // 2) fused LN1+shift+window+QKV+attention -> d_out (natural order)
    winattn_k<<<dim3(6, 2048), 256, 0, stream>>>(x, n1g, n1b, qkvP, qkv_b,
                                                 bmT, mb, rb, out);
    // 3) x1 = attn @ proj_w + proj_b + x   (in place on d_out)
    proj_k<<<T / 64, 256, 0, stream>>>(out, projP, proj_b, x, out);
    // 4) out = x1 + GELU(LN2(x1)@fc1+b1)@fc2 + b2   (in place, LN2 fused)
    mlp_k<<<T / 64, 256, 0, stream>>>(out, n2g, n2b, fc1P, fc1_b,
                                      fc2P, fc2_b, out);
}

// Round 5
// 829.845 us; speedup vs baseline: 2.9448x; 1.2797x over previous
//
#include <hip/hip_runtime.h>
#include <math.h>

// ---------------------------------------------------------------------------
// Swin block, bf16-MFMA, MI355X. B=32 H=W=56 C=192 NH=6 hd=32 WS=7 SS=3.
// T=100352. GEMMs: 16x16x32 bf16 MFMA, fp32 accum. LN/softmax/GELU/residual
// in fp32. Weights repacked per-launch into MFMA B-fragment order (bf16) in
// ws; B-frags load straight global->VGPR (16B/lane coalesced, L2-resident).
// Round 5: winattn_k restructured -- one block per window, MFMA attention.
// ---------------------------------------------------------------------------

constexpr long T = 100352;

typedef __attribute__((ext_vector_type(8))) short short8;   // 8 bf16
typedef __attribute__((ext_vector_type(4))) float f32x4;    // MFMA acc

__device__ __forceinline__ short bf16(float f) {
    union { float f; unsigned u; } v; v.f = f;
    return (short)((v.u + 0x7fff + ((v.u >> 16) & 1)) >> 16);
}

// B-fragment pack: element (k,n) of a KxN row-major weight ->
// flat = ((ntile*Kst + kstep)*64 + lane)*8 + k%8, lane = (n&15) + 16*((k>>3)&3)
template<int K, int N>
__global__ __launch_bounds__(256)
void pack_k(const float* __restrict__ W, short* __restrict__ P)
{
    const int idx = blockIdx.x * 256 + threadIdx.x;   // = k*N + n
    const int k = idx / N, n = idx - k * N;
    constexpr int Kst = K / 32;
    const int flat = (((n >> 4) * Kst + (k >> 5)) * 64 +
                      (((k >> 3) & 3) << 4) + (n & 15)) * 8 + (k & 7);
    P[flat] = bf16(W[idx]);
}

// combined rel-pos-bias + shift-mask table: [head][th][tw][i*49+j]
__global__ __launch_bounds__(256)
void biasprep_k(const float* __restrict__ relb, float* __restrict__ bm)
{
    const int idx = blockIdx.x * 256 + threadIdx.x;
    if (idx >= 6 * 4 * 2401) return;
    const int e = idx % 2401, rest = idx / 2401;
    const int tw = rest & 1, th = (rest >> 1) & 1, head = rest >> 2;
    const int i = e / 49, j = e - i * 49;
    const int yi = i / 7, xi = i - yi * 7, yj = j / 7, xj = j - yj * 7;
    const float v = relb[((yi - yj + 6) * 13 + (xi - xj + 6)) * 6 + head];
    const int hi = th ? 49 + yi : yi, hj = th ? 49 + yj : yj;
    const int wa = tw ? 49 + xi : xi, wb = tw ? 49 + xj : xj;
    const int Li = (hi < 49 ? 0 : (hi < 53 ? 1 : 2)) * 3 + (wa < 49 ? 0 : (wa < 53 ? 1 : 2));
    const int Lj = (hj < 49 ? 0 : (hj < 53 ? 1 : 2)) * 3 + (wb < 49 ? 0 : (wb < 53 ? 1 : 2));
    bm[idx] = (Li != Lj) ? v - 100.0f : v;
}

// ---------------- per-token LayerNorm stats (mean, rstd) — LN1 only --------
__global__ __launch_bounds__(256)
void lnstats_k(const float* __restrict__ x, float* __restrict__ mean,
               float* __restrict__ rstd)
{
    const int wave = threadIdx.x >> 6;
    const int lane = threadIdx.x & 63;
    const long tok = (long)blockIdx.x * 4 + wave;
    const float* p = x + tok * 192;
    const float a = p[lane], b = p[lane + 64], c = p[lane + 128];
    float s = a + b + c;
    float q = a * a + b * b + c * c;
    #pragma unroll
    for (int off = 32; off > 0; off >>= 1) {
        s += __shfl_xor(s, off);
        q += __shfl_xor(q, off);
    }
    if (lane == 0) {
        const float m = s * (1.0f / 192.0f);
        const float v = q * (1.0f / 192.0f) - m * m;
        mean[tok] = m;
        rstd[tok] = 1.0f / sqrtf(v + 1e-5f);
    }
}

// ---------------- fused LN1+shift+window+QKV+MFMA attention ----------------
// One block per window (2048 blocks), 4 waves = 4 M-tiles of 16 rows.
// Phase 1: A-frags (LN1 gather) in registers; QKV GEMM M64 N576 K192;
//          K,V epilogue-written as B-frags in LDS; Q transposed to regs via
//          2KB wave-private scratch. Phase 2 (per head): S=QK^T via MFMA,
//          softmax in C-layout regs (16-lane shuffles), P->A-frag round trip,
//          PV via MFMA, store natural order. One __syncthreads total.
__global__ __launch_bounds__(256)
void winattn_k(const float* __restrict__ x, const float* __restrict__ n1g,
               const float* __restrict__ n1b, const short* __restrict__ qkvP,
               const float* __restrict__ qkv_b, const float* __restrict__ bm,
               const float* __restrict__ mean, const float* __restrict__ rstd,
               float* __restrict__ outp)
{
    __shared__ __align__(16) short Kf[6][2048];   // per-head K B-frag (j=64pad, d=32)
    __shared__ __align__(16) short Vf[6][2048];   // per-head V B-frag (k=j 64pad, n=d 32)
    __shared__ __align__(16) short Pf[4][1024];   // per-wave A-frag scratch (16x64)
    const int bw  = blockIdx.x;    // 0..2047
    const int tid = threadIdx.x;
    const int b = bw >> 6, wi = bw & 63, wh = wi >> 3, ww = wi & 7;
    const int wave = tid >> 6, lane = tid & 63;
    const int col = lane & 15, rbase = (lane >> 4) << 2;
    const float scale = 0.17677669529663687f;   // 32^-0.5

    // ---- Phase 1a: A-fragments (LN1 + shift/window gather), registers ----
    const int am = lane & 15;            // A-frag row within mtile
    const int arow = (wave << 4) + am;   // 0..63
    const int kof = (lane >> 4) << 3;    // k sub-offset 0,8,16,24
    short8 afr[6];
    long tokA = 0; float mA = 0.f, rsA = 1.f;
    const bool avalid = arow < 49;
    if (avalid) {
        const int yi = arow / 7, xi = arow - yi * 7;
        int h = wh * 7 + yi + 3; if (h >= 56) h -= 56;
        int w = ww * 7 + xi + 3; if (w >= 56) w -= 56;
        tokA = (long)b * 3136 + h * 56 + w;
        mA = mean[tokA]; rsA = rstd[tokA];
    }
    #pragma unroll
    for (int ks = 0; ks < 6; ++ks) {
        short8 a = {};
        if (avalid) {
            const int k0 = (ks << 5) + kof;
            const float4 v0 = *(const float4*)(x + tokA * 192 + k0);
            const float4 v1 = *(const float4*)(x + tokA * 192 + k0 + 4);
            const float4 g0 = *(const float4*)(n1g + k0);
            const float4 g1 = *(const float4*)(n1g + k0 + 4);
            const float4 e0 = *(const float4*)(n1b + k0);
            const float4 e1 = *(const float4*)(n1b + k0 + 4);
            a[0] = bf16((v0.x - mA) * rsA * g0.x + e0.x);
            a[1] = bf16((v0.y - mA) * rsA * g0.y + e0.y);
            a[2] = bf16((v0.z - mA) * rsA * g0.z + e0.z);
            a[3] = bf16((v0.w - mA) * rsA * g0.w + e0.w);
            a[4] = bf16((v1.x - mA) * rsA * g1.x + e1.x);
            a[5] = bf16((v1.y - mA) * rsA * g1.y + e1.y);
            a[6] = bf16((v1.z - mA) * rsA * g1.z + e1.z);
            a[7] = bf16((v1.w - mA) * rsA * g1.w + e1.w);
        }
        afr[ks] = a;
    }

    // ---- Phase 1b: QKV GEMM, epilogue to frag layouts ----
    short8 qfrag[6];
    // Q ntiles 0..11: write C-tile into wave scratch (A-frag layout), read back
    #pragma unroll
    for (int nt = 0; nt < 12; ++nt) {
        f32x4 acc = {};
        #pragma unroll
        for (int ks = 0; ks < 6; ++ks) {
            const short8 bfr = *(const short8*)(qkvP + ((nt * 6 + ks) * 64 + lane) * 8);
            acc = __builtin_amdgcn_mfma_f32_16x16x32_bf16(afr[ks], bfr, acc, 0, 0, 0);
        }
        const int hh = nt >> 1, d = ((nt & 1) << 4) + col;
        const float bias = qkv_b[hh * 32 + d];
        #pragma unroll
        for (int r = 0; r < 4; ++r) {
            const int m = rbase + r;
            Pf[wave][((m + (((d >> 3) & 3) << 4)) << 3) + (d & 7)] =
                bf16((acc[r] + bias) * scale);
        }
        if (nt & 1) qfrag[hh] = *(const short8*)&Pf[wave][lane << 3];
    }
    // K ntiles 12..23 -> Kf B-frag: element (j, d)
    #pragma unroll
    for (int nt = 0; nt < 12; ++nt) {
        f32x4 acc = {};
        #pragma unroll
        for (int ks = 0; ks < 6; ++ks) {
            const short8 bfr = *(const short8*)(qkvP + (((nt + 12) * 6 + ks) * 64 + lane) * 8);
            acc = __builtin_amdgcn_mfma_f32_16x16x32_bf16(afr[ks], bfr, acc, 0, 0, 0);
        }
        const int hh = nt >> 1, d = ((nt & 1) << 4) + col;
        const float bias = qkv_b[192 + hh * 32 + d];
        #pragma unroll
        for (int r = 0; r < 4; ++r) {
            const int m = rbase + r;     // j = wave*16 + m
            Kf[hh][(((wave << 6) + m + (((d >> 3) & 3) << 4)) << 3) + (d & 7)] =
                bf16(acc[r] + bias);
        }
    }
    // V ntiles 24..35 -> Vf B-frag: element (k=j, n=d)
    #pragma unroll
    for (int nt = 0; nt < 12; ++nt) {
        f32x4 acc = {};
        #pragma unroll
        for (int ks = 0; ks < 6; ++ks) {
            const short8 bfr = *(const short8*)(qkvP + (((nt + 24) * 6 + ks) * 64 + lane) * 8);
            acc = __builtin_amdgcn_mfma_f32_16x16x32_bf16(afr[ks], bfr, acc, 0, 0, 0);
        }
        const int hh = nt >> 1, dt = nt & 1, d = (dt << 4) + col;
        const float bias = qkv_b[384 + hh * 32 + d];
        #pragma unroll
        for (int r = 0; r < 4; ++r) {
            const int m = rbase + r;     // j = wave*16 + m
            const int flat = ((((dt << 1) + (wave >> 1)) << 6) + col +
                              ((((wave << 1) + (m >> 3)) & 3) << 4)) * 8 + (m & 7);
            Vf[hh][flat] = bf16(acc[r] + bias);
        }
    }
    __syncthreads();

    // ---- Phase 2: attention, wave w handles rows [16w,16w+16) of all heads
    long tok_r[4]; bool iv[4]; int i49[4];
    #pragma unroll
    for (int r = 0; r < 4; ++r) {
        const int i = (wave << 4) + rbase + r;
        iv[r] = i < 49;
        i49[r] = iv[r] ? i * 49 : 0;
        if (iv[r]) {
            const int yi = i / 7, xi = i - yi * 7;
            int h = wh * 7 + yi + 3; if (h >= 56) h -= 56;
            int w = ww * 7 + xi + 3; if (w >= 56) w -= 56;
            tok_r[r] = (long)b * 3136 + h * 56 + w;
        } else tok_r[r] = 0;
    }

    for (int h = 0; h < 6; ++h) {
        const float* bmp = bm + (((h << 1) + (wh == 7)) * 2 + (ww == 7)) * 2401;
        f32x4 sa[4];
        #pragma unroll
        for (int jt = 0; jt < 4; ++jt) {
            f32x4 z = {};
            const short8 kfr = *(const short8*)&Kf[h][((jt << 6) + lane) << 3];
            sa[jt] = __builtin_amdgcn_mfma_f32_16x16x32_bf16(qfrag[h], kfr, z, 0, 0, 0);
        }
        // bias/mask + softmax in C layout
        float p[4][4];
        #pragma unroll
        for (int jt = 0; jt < 4; ++jt) {
            const int j = (jt << 4) + col;
            #pragma unroll
            for (int r = 0; r < 4; ++r)
                p[jt][r] = (j < 49) ? sa[jt][r] + bmp[i49[r] + j] : -1e30f;
        }
        #pragma unroll
        for (int r = 0; r < 4; ++r) {
            float mx = fmaxf(fmaxf(p[0][r], p[1][r]), fmaxf(p[2][r], p[3][r]));
            mx = fmaxf(mx, __shfl_xor(mx, 1));
            mx = fmaxf(mx, __shfl_xor(mx, 2));
            mx = fmaxf(mx, __shfl_xor(mx, 4));
            mx = fmaxf(mx, __shfl_xor(mx, 8));
            float sum = 0.f;
            #pragma unroll
            for (int jt = 0; jt < 4; ++jt) {
                const float e = (((jt << 4) + col) < 49) ? __expf(p[jt][r] - mx) : 0.f;
                p[jt][r] = e; sum += e;
            }
            sum += __shfl_xor(sum, 1);
            sum += __shfl_xor(sum, 2);
            sum += __shfl_xor(sum, 4);
            sum += __shfl_xor(sum, 8);
            const float inv = 1.0f / sum;
            #pragma unroll
            for (int jt = 0; jt < 4; ++jt) p[jt][r] *= inv;
        }
        // P -> A-frag via wave scratch
        #pragma unroll
        for (int jt = 0; jt < 4; ++jt) {
            #pragma unroll
            for (int r = 0; r < 4; ++r) {
                const int m = rbase + r;
                const int flat = (((jt >> 1) << 6) + m +
                                  ((((jt & 1) << 1) + (col >> 3)) << 4)) * 8 + (col & 7);
                Pf[wave][flat] = bf16(p[jt][r]);
            }
        }
        const short8 p0 = *(const short8*)&Pf[wave][lane << 3];
        const short8 p1 = *(const short8*)&Pf[wave][(64 + lane) << 3];
        f32x4 oa[2] = {};
        #pragma unroll
        for (int dt = 0; dt < 2; ++dt) {
            const short8 v0 = *(const short8*)&Vf[h][(((dt << 1) << 6) + lane) << 3];
            const short8 v1 = *(const short8*)&Vf[h][((((dt << 1) + 1) << 6) + lane) << 3];
            oa[dt] = __builtin_amdgcn_mfma_f32_16x16x32_bf16(p0, v0, oa[dt], 0, 0, 0);
            oa[dt] = __builtin_amdgcn_mfma_f32_16x16x32_bf16(p1, v1, oa[dt], 0, 0, 0);
        }
        #pragma unroll
        for (int dt = 0; dt < 2; ++dt)
            #pragma unroll
            for (int r = 0; r < 4; ++r)
                if (iv[r])
                    outp[tok_r[r] * 192 + h * 32 + (dt << 4) + col] = oa[dt][r];
    }
}

// ---------------- proj GEMM (MFMA) + residual, in place on d_out -----------
__global__ __launch_bounds__(256)
void proj_k(const float* attnb, const short* __restrict__ projP,
            const float* __restrict__ pb, const float* __restrict__ x,
            float* outp)
{
    __shared__ __align__(16) short As[12288];   // 64x192 A-pack
    const int tid = threadIdx.x;
    const int wave = tid >> 6, lane = tid & 63;
    const long m0 = (long)blockIdx.x * 64;

    for (int idx = tid; idx < 3072; idx += 256) {   // 64 rows x 48 float4
        const int m = idx / 48, q4 = idx - m * 48, k0 = q4 * 4;
        const float4 v = *(const float4*)(attnb + (m0 + m) * 192 + k0);
        const short4 s4 = make_short4(bf16(v.x), bf16(v.y), bf16(v.z), bf16(v.w));
        const int flat = (((m >> 4) * 6 + (k0 >> 5)) * 64 +
                          (((k0 >> 3) & 3) << 4) + (m & 15)) * 8 + (k0 & 7);
        *(short4*)&As[flat] = s4;
    }
    __syncthreads();

    f32x4 acc[12] = {};
    for (int ks = 0; ks < 6; ++ks) {
        const short8 a = *(const short8*)&As[((wave * 6 + ks) << 9) + (lane << 3)];
        #pragma unroll
        for (int nt = 0; nt < 12; ++nt) {
            const short8 bfr = *(const short8*)(projP + ((nt * 6 + ks) * 64 + lane) * 8);
            acc[nt] = __builtin_amdgcn_mfma_f32_16x16x32_bf16(a, bfr, acc[nt], 0, 0, 0);
        }
    }

    const int col = lane & 15, rbase = (lane >> 4) << 2;
    #pragma unroll
    for (int nt = 0; nt < 12; ++nt) {
        const int n = (nt << 4) + col;
        const float bias = pb[n];
        #pragma unroll
        for (int r = 0; r < 4; ++r) {
            const long row = m0 + (wave << 4) + rbase + r;
            outp[row * 192 + n] = acc[nt][r] + bias + x[row * 192 + n];
        }
    }
}

// ---------------- fused MLP (MFMA): out = x1 + GELU(LN2(x1)@W1+b1)@W2+b2 ---
__global__ __launch_bounds__(256)
void mlp_k(const float* x1, const float* __restrict__ n2g,
           const float* __restrict__ n2b, const short* __restrict__ fc1P,
           const float* __restrict__ b1, const short* __restrict__ fc2P,
           const float* __restrict__ b2, float* outp)
{
    __shared__ __align__(16) short As[12288];   // LN2(x1) 64x192 A-pack
    __shared__ __align__(16) short Hs[4096];    // H 64x64 A-pack (per-wave mtile)
    const int tid = threadIdx.x;
    const int wave = tid >> 6, lane = tid & 63;
    const long m0 = (long)blockIdx.x * 64;

    // LN2 stats + pack: 4 threads per row
    {
        const int row = tid >> 2, seg = tid & 3;
        const float* xp = x1 + (m0 + row) * 192;
        float s = 0.f, q = 0.f;
        #pragma unroll
        for (int c = 0; c < 12; ++c) {
            const float4 v = *(const float4*)(xp + ((c << 2) + seg) * 4);
            s += v.x + v.y + v.z + v.w;
            q += v.x * v.x + v.y * v.y + v.z * v.z + v.w * v.w;
        }
        s += __shfl_xor(s, 1); s += __shfl_xor(s, 2);
        q += __shfl_xor(q, 1); q += __shfl_xor(q, 2);
        const float m_ = s * (1.0f / 192.0f);
        const float rs_ = rsqrtf(q * (1.0f / 192.0f) - m_ * m_ + 1e-5f);
        const int mt = row >> 4, ml = row & 15;
        #pragma unroll
        for (int c = 0; c < 12; ++c) {
            const int k0 = ((c << 2) + seg) * 4;
            const float4 v  = *(const float4*)(xp + k0);
            const float4 g  = *(const float4*)(n2g + k0);
            const float4 be = *(const float4*)(n2b + k0);
            const short4 s4 = make_short4(
                bf16((v.x - m_) * rs_ * g.x + be.x), bf16((v.y - m_) * rs_ * g.y + be.y),
                bf16((v.z - m_) * rs_ * g.z + be.z), bf16((v.w - m_) * rs_ * g.w + be.w));
            const int flat = ((mt * 6 + (k0 >> 5)) * 64 +
                              (((k0 >> 3) & 3) << 4) + ml) * 8 + (k0 & 7);
            *(short4*)&As[flat] = s4;
        }
    }
    __syncthreads();

    const int col = lane & 15, rbase = (lane >> 4) << 2;
    f32x4 accO[12] = {};
    for (int t = 0; t < 12; ++t) {
        f32x4 accH[4] = {};
        for (int ks = 0; ks < 6; ++ks) {
            const short8 a = *(const short8*)&As[((wave * 6 + ks) << 9) + (lane << 3)];
            #pragma unroll
            for (int nt = 0; nt < 4; ++nt) {
                const short8 bfr = *(const short8*)(fc1P + ((((t << 2) + nt) * 6 + ks) * 64 + lane) * 8);
                accH[nt] = __builtin_amdgcn_mfma_f32_16x16x32_bf16(a, bfr, accH[nt], 0, 0, 0);
            }
        }
        #pragma unroll
        for (int nt = 0; nt < 4; ++nt) {
            const int kh = (nt << 4) + col;
            const float bias = b1[(t << 6) + kh];
            #pragma unroll
            for (int r = 0; r < 4; ++r) {
                const int m = (wave << 4) + rbase + r;
                float val = accH[nt][r] + bias;
                val = 0.5f * val * (1.0f + erff(val * 0.7071067811865476f));
                const int flat = (((wave << 1) + (kh >> 5)) * 64 +
                                  (((kh >> 3) & 3) << 4) + (m & 15)) * 8 + (kh & 7);
                Hs[flat] = bf16(val);
            }
        }
        #pragma unroll
        for (int ks = 0; ks < 2; ++ks) {
            const short8 a = *(const short8*)&Hs[(((wave << 1) + ks) << 9) + (lane << 3)];
            #pragma unroll
            for (int nt = 0; nt < 12; ++nt) {
                const short8 bfr = *(const short8*)(fc2P + ((nt * 24 + (t << 1) + ks) * 64 + lane) * 8);
                accO[nt] = __builtin_amdgcn_mfma_f32_16x16x32_bf16(a, bfr, accO[nt], 0, 0, 0);
            }
        }
    }

    #pragma unroll
    for (int nt = 0; nt < 12; ++nt) {
        const int n = (nt << 4) + col;
        const float bias = b2[n];
        #pragma unroll
        for (int r = 0; r < 4; ++r) {
            const long row = m0 + (wave << 4) + rbase + r;
            outp[row * 192 + n] = accO[nt][r] + bias + x1[row * 192 + n];
        }
    }
}

// ---------------------------------------------------------------------------
extern "C" void kernel_launch(void* const* d_in, const int* in_sizes, int n_in,
                              void* d_out, int out_size, void* d_ws, size_t ws_size,
                              hipStream_t stream)
{
    const float* x      = (const float*)d_in[0];
    const float* n1g    = (const float*)d_in[1];
    const float* n1b    = (const float*)d_in[2];
    const float* qkv_w  = (const float*)d_in[3];
    const float* qkv_b  = (const float*)d_in[4];
    const float* relb   = (const float*)d_in[5];
    const float* proj_w = (const float*)d_in[6];
    const float* proj_b = (const float*)d_in[7];
    const float* n2g    = (const float*)d_in[8];
    const float* n2b    = (const float*)d_in[9];
    const float* fc1_w  = (const float*)d_in[10];
    const float* fc1_b  = (const float*)d_in[11];
    const float* fc2_w  = (const float*)d_in[12];
    const float* fc2_b  = (const float*)d_in[13];
    float* out = (float*)d_out;
    char*  ws  = (char*)d_ws;

    float* mb    = (float*)(ws);                   //   401,408 B
    float* rb    = (float*)(ws +   401408L);       //   401,408 B
    short* qkvP  = (short*)(ws +   802816L);       //   221,184 B
    short* projP = (short*)(ws +  1024000L);       //    73,728 B
    short* fc1P  = (short*)(ws +  1097728L);       //   294,912 B
    short* fc2P  = (short*)(ws +  1392640L);       //   294,912 B
    float* bmT   = (float*)(ws +  1687552L);       //   230,496 B  (~1.92 MB total)

    pack_k<192, 576><<<432, 256, 0, stream>>>(qkv_w, qkvP);
    pack_k<192, 192><<<144, 256, 0, stream>>>(proj_w, projP);
    pack_k<192, 768><<<576, 256, 0, stream>>>(fc1_w, fc1P);
    pack_k<768, 192><<<576, 256, 0, stream>>>(fc2_w, fc2P);
    biasprep_k<<<226, 256, 0, stream>>>(relb, bmT);

    // 1) LN1 stats
    lnstats_k<<<T / 4, 256, 0, stream>>>(x, mb, rb);
    // 2) fused LN1+shift+window+QKV+MFMA attention -> d_out (natural order)
    winattn_k<<<2048, 256, 0, stream>>>(x, n1g, n1b, qkvP, qkv_b,
                                        bmT, mb, rb, out);
    // 3) x1 = attn @ proj_w + proj_b + x   (in place on d_out)
    proj_k<<<T / 64, 256, 0, stream>>>(out, projP, proj_b, x, out);
    // 4) out = x1 + GELU(LN2(x1)@fc1+b1)@fc2 + b2   (in place, LN2 fused)
    mlp_k<<<T / 64, 256, 0, stream>>>(out, n2g, n2b, fc1P, fc1_b,
                                      fc2P, fc2_b, out);
}

// Round 6
// 620.139 us; speedup vs baseline: 3.9406x; 1.3382x over previous
//
#include <hip/hip_runtime.h>
#include <math.h>

// ---------------------------------------------------------------------------
// Swin block, bf16-MFMA, MI355X. B=32 H=W=56 C=192 NH=6 hd=32 WS=7 SS=3.
// T=100352. GEMMs: 16x16x32 bf16 MFMA, fp32 accum. LN/softmax/GELU/residual
// in fp32. Weights repacked per-launch into MFMA B-fragment order (bf16).
// Round 6: mlp_k/proj_k stage B-tiles in LDS (per-block, not per-wave);
// mlp LN2 -> register A-frags (no As LDS); fc2/proj pack orders changed
// so each staged tile is one contiguous region.
// ---------------------------------------------------------------------------

constexpr long T = 100352;

typedef __attribute__((ext_vector_type(8))) short short8;   // 8 bf16
typedef __attribute__((ext_vector_type(4))) float f32x4;    // MFMA acc

__device__ __forceinline__ short bf16(float f) {
    union { float f; unsigned u; } v; v.f = f;
    return (short)((v.u + 0x7fff + ((v.u >> 16) & 1)) >> 16);
}

// B-fragment pack (qkv, fc1): element (k,n) of KxN row-major ->
// flat = ((ntile*Kst + kstep)*64 + lane)*8 + k%8, lane = (n&15) + 16*((k>>3)&3)
template<int K, int N>
__global__ __launch_bounds__(256)
void pack_k(const float* __restrict__ W, short* __restrict__ P)
{
    const int idx = blockIdx.x * 256 + threadIdx.x;   // = k*N + n
    const int k = idx / N, n = idx - k * N;
    constexpr int Kst = K / 32;
    const int flat = (((n >> 4) * Kst + (k >> 5)) * 64 +
                      (((k >> 3) & 3) << 4) + (n & 15)) * 8 + (k & 7);
    P[flat] = bf16(W[idx]);
}

// fc2 pack: [t][nt][ks] so each t's 24KB tile is contiguous. K=768,N=192.
__global__ __launch_bounds__(256)
void pack_fc2_k(const float* __restrict__ W, short* __restrict__ P)
{
    const int idx = blockIdx.x * 256 + threadIdx.x;   // k*192 + n
    const int k = idx / 192, n = idx - k * 192;
    const int t = k >> 6, ks = (k >> 5) & 1, nt = n >> 4;
    const int flat = ((((t * 12 + nt) << 1) + ks) * 64 +
                      (((k >> 3) & 3) << 4) + (n & 15)) * 8 + (k & 7);
    P[flat] = bf16(W[idx]);
}

// proj pack: [ks][nt] so each k-step's 12KB tile is contiguous. K=192,N=192.
__global__ __launch_bounds__(256)
void pack_proj_k(const float* __restrict__ W, short* __restrict__ P)
{
    const int idx = blockIdx.x * 256 + threadIdx.x;   // k*192 + n
    const int k = idx / 192, n = idx - k * 192;
    const int ks = k >> 5, nt = n >> 4;
    const int flat = (((ks * 12 + nt) * 64) +
                      (((k >> 3) & 3) << 4) + (n & 15)) * 8 + (k & 7);
    P[flat] = bf16(W[idx]);
}

// combined rel-pos-bias + shift-mask table: [head][th][tw][i*49+j]
__global__ __launch_bounds__(256)
void biasprep_k(const float* __restrict__ relb, float* __restrict__ bm)
{
    const int idx = blockIdx.x * 256 + threadIdx.x;
    if (idx >= 6 * 4 * 2401) return;
    const int e = idx % 2401, rest = idx / 2401;
    const int tw = rest & 1, th = (rest >> 1) & 1, head = rest >> 2;
    const int i = e / 49, j = e - i * 49;
    const int yi = i / 7, xi = i - yi * 7, yj = j / 7, xj = j - yj * 7;
    const float v = relb[((yi - yj + 6) * 13 + (xi - xj + 6)) * 6 + head];
    const int hi = th ? 49 + yi : yi, hj = th ? 49 + yj : yj;
    const int wa = tw ? 49 + xi : xi, wb = tw ? 49 + xj : xj;
    const int Li = (hi < 49 ? 0 : (hi < 53 ? 1 : 2)) * 3 + (wa < 49 ? 0 : (wa < 53 ? 1 : 2));
    const int Lj = (hj < 49 ? 0 : (hj < 53 ? 1 : 2)) * 3 + (wb < 49 ? 0 : (wb < 53 ? 1 : 2));
    bm[idx] = (Li != Lj) ? v - 100.0f : v;
}

// ---------------- per-token LayerNorm stats (mean, rstd) — LN1 only --------
__global__ __launch_bounds__(256)
void lnstats_k(const float* __restrict__ x, float* __restrict__ mean,
               float* __restrict__ rstd)
{
    const int wave = threadIdx.x >> 6;
    const int lane = threadIdx.x & 63;
    const long tok = (long)blockIdx.x * 4 + wave;
    const float* p = x + tok * 192;
    const float a = p[lane], b = p[lane + 64], c = p[lane + 128];
    float s = a + b + c;
    float q = a * a + b * b + c * c;
    #pragma unroll
    for (int off = 32; off > 0; off >>= 1) {
        s += __shfl_xor(s, off);
        q += __shfl_xor(q, off);
    }
    if (lane == 0) {
        const float m = s * (1.0f / 192.0f);
        const float v = q * (1.0f / 192.0f) - m * m;
        mean[tok] = m;
        rstd[tok] = 1.0f / sqrtf(v + 1e-5f);
    }
}

// ---------------- fused LN1+shift+window+QKV+MFMA attention ----------------
// (unchanged from round 5)
__global__ __launch_bounds__(256)
void winattn_k(const float* __restrict__ x, const float* __restrict__ n1g,
               const float* __restrict__ n1b, const short* __restrict__ qkvP,
               const float* __restrict__ qkv_b, const float* __restrict__ bm,
               const float* __restrict__ mean, const float* __restrict__ rstd,
               float* __restrict__ outp)
{
    __shared__ __align__(16) short Kf[6][2048];
    __shared__ __align__(16) short Vf[6][2048];
    __shared__ __align__(16) short Pf[4][1024];
    const int bw  = blockIdx.x;
    const int tid = threadIdx.x;
    const int b = bw >> 6, wi = bw & 63, wh = wi >> 3, ww = wi & 7;
    const int wave = tid >> 6, lane = tid & 63;
    const int col = lane & 15, rbase = (lane >> 4) << 2;
    const float scale = 0.17677669529663687f;

    const int am = lane & 15;
    const int arow = (wave << 4) + am;
    const int kof = (lane >> 4) << 3;
    short8 afr[6];
    long tokA = 0; float mA = 0.f, rsA = 1.f;
    const bool avalid = arow < 49;
    if (avalid) {
        const int yi = arow / 7, xi = arow - yi * 7;
        int h = wh * 7 + yi + 3; if (h >= 56) h -= 56;
        int w = ww * 7 + xi + 3; if (w >= 56) w -= 56;
        tokA = (long)b * 3136 + h * 56 + w;
        mA = mean[tokA]; rsA = rstd[tokA];
    }
    #pragma unroll
    for (int ks = 0; ks < 6; ++ks) {
        short8 a = {};
        if (avalid) {
            const int k0 = (ks << 5) + kof;
            const float4 v0 = *(const float4*)(x + tokA * 192 + k0);
            const float4 v1 = *(const float4*)(x + tokA * 192 + k0 + 4);
            const float4 g0 = *(const float4*)(n1g + k0);
            const float4 g1 = *(const float4*)(n1g + k0 + 4);
            const float4 e0 = *(const float4*)(n1b + k0);
            const float4 e1 = *(const float4*)(n1b + k0 + 4);
            a[0] = bf16((v0.x - mA) * rsA * g0.x + e0.x);
            a[1] = bf16((v0.y - mA) * rsA * g0.y + e0.y);
            a[2] = bf16((v0.z - mA) * rsA * g0.z + e0.z);
            a[3] = bf16((v0.w - mA) * rsA * g0.w + e0.w);
            a[4] = bf16((v1.x - mA) * rsA * g1.x + e1.x);
            a[5] = bf16((v1.y - mA) * rsA * g1.y + e1.y);
            a[6] = bf16((v1.z - mA) * rsA * g1.z + e1.z);
            a[7] = bf16((v1.w - mA) * rsA * g1.w + e1.w);
        }
        afr[ks] = a;
    }

    short8 qfrag[6];
    #pragma unroll
    for (int nt = 0; nt < 12; ++nt) {
        f32x4 acc = {};
        #pragma unroll
        for (int ks = 0; ks < 6; ++ks) {
            const short8 bfr = *(const short8*)(qkvP + ((nt * 6 + ks) * 64 + lane) * 8);
            acc = __builtin_amdgcn_mfma_f32_16x16x32_bf16(afr[ks], bfr, acc, 0, 0, 0);
        }
        const int hh = nt >> 1, d = ((nt & 1) << 4) + col;
        const float bias = qkv_b[hh * 32 + d];
        #pragma unroll
        for (int r = 0; r < 4; ++r) {
            const int m = rbase + r;
            Pf[wave][((m + (((d >> 3) & 3) << 4)) << 3) + (d & 7)] =
                bf16((acc[r] + bias) * scale);
        }
        if (nt & 1) qfrag[hh] = *(const short8*)&Pf[wave][lane << 3];
    }
    #pragma unroll
    for (int nt = 0; nt < 12; ++nt) {
        f32x4 acc = {};
        #pragma unroll
        for (int ks = 0; ks < 6; ++ks) {
            const short8 bfr = *(const short8*)(qkvP + (((nt + 12) * 6 + ks) * 64 + lane) * 8);
            acc = __builtin_amdgcn_mfma_f32_16x16x32_bf16(afr[ks], bfr, acc, 0, 0, 0);
        }
        const int hh = nt >> 1, d = ((nt & 1) << 4) + col;
        const float bias = qkv_b[192 + hh * 32 + d];
        #pragma unroll
        for (int r = 0; r < 4; ++r) {
            const int m = rbase + r;
            Kf[hh][(((wave << 6) + m + (((d >> 3) & 3) << 4)) << 3) + (d & 7)] =
                bf16(acc[r] + bias);
        }
    }
    #pragma unroll
    for (int nt = 0; nt < 12; ++nt) {
        f32x4 acc = {};
        #pragma unroll
        for (int ks = 0; ks < 6; ++ks) {
            const short8 bfr = *(const short8*)(qkvP + (((nt + 24) * 6 + ks) * 64 + lane) * 8);
            acc = __builtin_amdgcn_mfma_f32_16x16x32_bf16(afr[ks], bfr, acc, 0, 0, 0);
        }
        const int hh = nt >> 1, dt = nt & 1, d = (dt << 4) + col;
        const float bias = qkv_b[384 + hh * 32 + d];
        #pragma unroll
        for (int r = 0; r < 4; ++r) {
            const int m = rbase + r;
            const int flat = ((((dt << 1) + (wave >> 1)) << 6) + col +
                              ((((wave << 1) + (m >> 3)) & 3) << 4)) * 8 + (m & 7);
            Vf[hh][flat] = bf16(acc[r] + bias);
        }
    }
    __syncthreads();

    long tok_r[4]; bool iv[4]; int i49[4];
    #pragma unroll
    for (int r = 0; r < 4; ++r) {
        const int i = (wave << 4) + rbase + r;
        iv[r] = i < 49;
        i49[r] = iv[r] ? i * 49 : 0;
        if (iv[r]) {
            const int yi = i / 7, xi = i - yi * 7;
            int h = wh * 7 + yi + 3; if (h >= 56) h -= 56;
            int w = ww * 7 + xi + 3; if (w >= 56) w -= 56;
            tok_r[r] = (long)b * 3136 + h * 56 + w;
        } else tok_r[r] = 0;
    }

    for (int h = 0; h < 6; ++h) {
        const float* bmp = bm + (((h << 1) + (wh == 7)) * 2 + (ww == 7)) * 2401;
        f32x4 sa[4];
        #pragma unroll
        for (int jt = 0; jt < 4; ++jt) {
            f32x4 z = {};
            const short8 kfr = *(const short8*)&Kf[h][((jt << 6) + lane) << 3];
            sa[jt] = __builtin_amdgcn_mfma_f32_16x16x32_bf16(qfrag[h], kfr, z, 0, 0, 0);
        }
        float p[4][4];
        #pragma unroll
        for (int jt = 0; jt < 4; ++jt) {
            const int j = (jt << 4) + col;
            #pragma unroll
            for (int r = 0; r < 4; ++r)
                p[jt][r] = (j < 49) ? sa[jt][r] + bmp[i49[r] + j] : -1e30f;
        }
        #pragma unroll
        for (int r = 0; r < 4; ++r) {
            float mx = fmaxf(fmaxf(p[0][r], p[1][r]), fmaxf(p[2][r], p[3][r]));
            mx = fmaxf(mx, __shfl_xor(mx, 1));
            mx = fmaxf(mx, __shfl_xor(mx, 2));
            mx = fmaxf(mx, __shfl_xor(mx, 4));
            mx = fmaxf(mx, __shfl_xor(mx, 8));
            float sum = 0.f;
            #pragma unroll
            for (int jt = 0; jt < 4; ++jt) {
                const float e = (((jt << 4) + col) < 49) ? __expf(p[jt][r] - mx) : 0.f;
                p[jt][r] = e; sum += e;
            }
            sum += __shfl_xor(sum, 1);
            sum += __shfl_xor(sum, 2);
            sum += __shfl_xor(sum, 4);
            sum += __shfl_xor(sum, 8);
            const float inv = 1.0f / sum;
            #pragma unroll
            for (int jt = 0; jt < 4; ++jt) p[jt][r] *= inv;
        }
        #pragma unroll
        for (int jt = 0; jt < 4; ++jt) {
            #pragma unroll
            for (int r = 0; r < 4; ++r) {
                const int m = rbase + r;
                const int flat = (((jt >> 1) << 6) + m +
                                  ((((jt & 1) << 1) + (col >> 3)) << 4)) * 8 + (col & 7);
                Pf[wave][flat] = bf16(p[jt][r]);
            }
        }
        const short8 p0 = *(const short8*)&Pf[wave][lane << 3];
        const short8 p1 = *(const short8*)&Pf[wave][(64 + lane) << 3];
        f32x4 oa[2] = {};
        #pragma unroll
        for (int dt = 0; dt < 2; ++dt) {
            const short8 v0 = *(const short8*)&Vf[h][(((dt << 1) << 6) + lane) << 3];
            const short8 v1 = *(const short8*)&Vf[h][((((dt << 1) + 1) << 6) + lane) << 3];
            oa[dt] = __builtin_amdgcn_mfma_f32_16x16x32_bf16(p0, v0, oa[dt], 0, 0, 0);
            oa[dt] = __builtin_amdgcn_mfma_f32_16x16x32_bf16(p1, v1, oa[dt], 0, 0, 0);
        }
        #pragma unroll
        for (int dt = 0; dt < 2; ++dt)
            #pragma unroll
            for (int r = 0; r < 4; ++r)
                if (iv[r])
                    outp[tok_r[r] * 192 + h * 32 + (dt << 4) + col] = oa[dt][r];
    }
}

// ---------------- proj GEMM (MFMA) + residual, in place on d_out -----------
// B staged per k-step in LDS ([ks][nt] pack order), loaded once per block.
__global__ __launch_bounds__(256)
void proj_k(const float* attnb, const short* __restrict__ projP,
            const float* __restrict__ pb, const float* __restrict__ x,
            float* outp)
{
    __shared__ __align__(16) short As[12288];   // 64x192 A-pack
    __shared__ __align__(16) short Bs[6144];    // 12 B-frags (one k-step)
    const int tid = threadIdx.x;
    const int wave = tid >> 6, lane = tid & 63;
    const long m0 = (long)blockIdx.x * 64;

    for (int idx = tid; idx < 3072; idx += 256) {   // 64 rows x 48 float4
        const int m = idx / 48, q4 = idx - m * 48, k0 = q4 * 4;
        const float4 v = *(const float4*)(attnb + (m0 + m) * 192 + k0);
        const short4 s4 = make_short4(bf16(v.x), bf16(v.y), bf16(v.z), bf16(v.w));
        const int flat = (((m >> 4) * 6 + (k0 >> 5)) * 64 +
                          (((k0 >> 3) & 3) << 4) + (m & 15)) * 8 + (k0 & 7);
        *(short4*)&As[flat] = s4;
    }

    f32x4 acc[12] = {};
    for (int ks = 0; ks < 6; ++ks) {
        __syncthreads();
        #pragma unroll
        for (int i = 0; i < 3; ++i)
            ((short8*)Bs)[tid + (i << 8)] =
                ((const short8*)(projP + ks * 6144))[tid + (i << 8)];
        __syncthreads();
        const short8 a = *(const short8*)&As[((wave * 6 + ks) << 9) + (lane << 3)];
        #pragma unroll
        for (int nt = 0; nt < 12; ++nt) {
            const short8 bfr = *(const short8*)&Bs[(nt << 9) + (lane << 3)];
            acc[nt] = __builtin_amdgcn_mfma_f32_16x16x32_bf16(a, bfr, acc[nt], 0, 0, 0);
        }
    }

    const int col = lane & 15, rbase = (lane >> 4) << 2;
    #pragma unroll
    for (int nt = 0; nt < 12; ++nt) {
        const int n = (nt << 4) + col;
        const float bias = pb[n];
        #pragma unroll
        for (int r = 0; r < 4; ++r) {
            const long row = m0 + (wave << 4) + rbase + r;
            outp[row * 192 + n] = acc[nt][r] + bias + x[row * 192 + n];
        }
    }
}

// ---------------- fused MLP (MFMA): out = x1 + GELU(LN2(x1)@W1+b1)@W2+b2 ---
// Block owns 64 rows (in place). LN2 -> register A-frags (no As LDS).
// Per t: stage fc1 24KB + fc2 24KB tiles in LDS once per block.
__global__ __launch_bounds__(256)
void mlp_k(const float* x1, const float* __restrict__ n2g,
           const float* __restrict__ n2b, const short* __restrict__ fc1P,
           const float* __restrict__ b1, const short* __restrict__ fc2P,
           const float* __restrict__ b2, float* outp)
{
    __shared__ __align__(16) short S1[12288];   // fc1 t-tile (4 nt x 6 ks)
    __shared__ __align__(16) short S2[12288];   // fc2 t-tile (12 nt x 2 ks)
    __shared__ __align__(16) short Hs[4096];    // per-wave H A-frag scratch
    const int tid = threadIdx.x;
    const int wave = tid >> 6, lane = tid & 63;
    const int col = lane & 15, rbase = (lane >> 4) << 2;
    const long m0 = (long)blockIdx.x * 64;

    // LN2 stats + A-frags in registers. Lane owns row (lane&15) of its wave's
    // mtile, k-range kof..kof+8 per ks. Stats reduced across lanes sharing
    // the row (xor 16, 32).
    const long arow = m0 + (wave << 4) + col;
    const int kof = (lane >> 4) << 3;
    const float* xp = x1 + arow * 192;
    float s = 0.f, q = 0.f;
    #pragma unroll
    for (int ks = 0; ks < 6; ++ks) {
        const int k0 = (ks << 5) + kof;
        const float4 v0 = *(const float4*)(xp + k0);
        const float4 v1 = *(const float4*)(xp + k0 + 4);
        s += v0.x + v0.y + v0.z + v0.w + v1.x + v1.y + v1.z + v1.w;
        q += v0.x * v0.x + v0.y * v0.y + v0.z * v0.z + v0.w * v0.w
           + v1.x * v1.x + v1.y * v1.y + v1.z * v1.z + v1.w * v1.w;
    }
    s += __shfl_xor(s, 16); s += __shfl_xor(s, 32);
    q += __shfl_xor(q, 16); q += __shfl_xor(q, 32);
    const float m_ = s * (1.0f / 192.0f);
    const float rs_ = rsqrtf(q * (1.0f / 192.0f) - m_ * m_ + 1e-5f);
    short8 afr[6];
    #pragma unroll
    for (int ks = 0; ks < 6; ++ks) {
        const int k0 = (ks << 5) + kof;
        const float4 v0 = *(const float4*)(xp + k0);
        const float4 v1 = *(const float4*)(xp + k0 + 4);
        const float4 g0 = *(const float4*)(n2g + k0);
        const float4 g1 = *(const float4*)(n2g + k0 + 4);
        const float4 e0 = *(const float4*)(n2b + k0);
        const float4 e1 = *(const float4*)(n2b + k0 + 4);
        short8 a;
        a[0] = bf16((v0.x - m_) * rs_ * g0.x + e0.x);
        a[1] = bf16((v0.y - m_) * rs_ * g0.y + e0.y);
        a[2] = bf16((v0.z - m_) * rs_ * g0.z + e0.z);
        a[3] = bf16((v0.w - m_) * rs_ * g0.w + e0.w);
        a[4] = bf16((v1.x - m_) * rs_ * g1.x + e1.x);
        a[5] = bf16((v1.y - m_) * rs_ * g1.y + e1.y);
        a[6] = bf16((v1.z - m_) * rs_ * g1.z + e1.z);
        a[7] = bf16((v1.w - m_) * rs_ * g1.w + e1.w);
        afr[ks] = a;
    }

    f32x4 accO[12] = {};
    for (int t = 0; t < 12; ++t) {
        __syncthreads();
        {   // stage both tiles: 1536 short8 each, 6 per thread
            const short8* src1 = (const short8*)(fc1P + t * 12288);
            const short8* src2 = (const short8*)(fc2P + t * 12288);
            short8* d1 = (short8*)S1;
            short8* d2 = (short8*)S2;
            #pragma unroll
            for (int i = 0; i < 6; ++i) {
                d1[tid + (i << 8)] = src1[tid + (i << 8)];
                d2[tid + (i << 8)] = src2[tid + (i << 8)];
            }
        }
        __syncthreads();
        // GEMM1: H(16x64 per wave) = A @ fc1_tile
        f32x4 accH[4] = {};
        #pragma unroll
        for (int ks = 0; ks < 6; ++ks) {
            #pragma unroll
            for (int nt = 0; nt < 4; ++nt) {
                const short8 bfr = *(const short8*)&S1[((nt * 6 + ks) << 9) + (lane << 3)];
                accH[nt] = __builtin_amdgcn_mfma_f32_16x16x32_bf16(afr[ks], bfr, accH[nt], 0, 0, 0);
            }
        }
        // bias + exact GELU -> Hs (wave-private A-frag layout)
        #pragma unroll
        for (int nt = 0; nt < 4; ++nt) {
            const int kh = (nt << 4) + col;
            const float bias = b1[(t << 6) + kh];
            #pragma unroll
            for (int r = 0; r < 4; ++r) {
                const int m = rbase + r;
                float val = accH[nt][r] + bias;
                val = 0.5f * val * (1.0f + erff(val * 0.7071067811865476f));
                const int flat = (((wave << 1) + (kh >> 5)) * 64 +
                                  (((kh >> 3) & 3) << 4) + m) * 8 + (kh & 7);
                Hs[flat] = bf16(val);
            }
        }
        // GEMM2: accO += H @ fc2_tile
        #pragma unroll
        for (int ks = 0; ks < 2; ++ks) {
            const short8 a = *(const short8*)&Hs[(((wave << 1) + ks) << 9) + (lane << 3)];
            #pragma unroll
            for (int nt = 0; nt < 12; ++nt) {
                const short8 bfr = *(const short8*)&S2[(((nt << 1) + ks) << 9) + (lane << 3)];
                accO[nt] = __builtin_amdgcn_mfma_f32_16x16x32_bf16(a, bfr, accO[nt], 0, 0, 0);
            }
        }
    }

    #pragma unroll
    for (int nt = 0; nt < 12; ++nt) {
        const int n = (nt << 4) + col;
        const float bias = b2[n];
        #pragma unroll
        for (int r = 0; r < 4; ++r) {
            const long row = m0 + (wave << 4) + rbase + r;
            outp[row * 192 + n] = accO[nt][r] + bias + x1[row * 192 + n];
        }
    }
}

// ---------------------------------------------------------------------------
extern "C" void kernel_launch(void* const* d_in, const int* in_sizes, int n_in,
                              void* d_out, int out_size, void* d_ws, size_t ws_size,
                              hipStream_t stream)
{
    const float* x      = (const float*)d_in[0];
    const float* n1g    = (const float*)d_in[1];
    const float* n1b    = (const float*)d_in[2];
    const float* qkv_w  = (const float*)d_in[3];
    const float* qkv_b  = (const float*)d_in[4];
    const float* relb   = (const float*)d_in[5];
    const float* proj_w = (const float*)d_in[6];
    const float* proj_b = (const float*)d_in[7];
    const float* n2g    = (const float*)d_in[8];
    const float* n2b    = (const float*)d_in[9];
    const float* fc1_w  = (const float*)d_in[10];
    const float* fc1_b  = (const float*)d_in[11];
    const float* fc2_w  = (const float*)d_in[12];
    const float* fc2_b  = (const float*)d_in[13];
    float* out = (float*)d_out;
    char*  ws  = (char*)d_ws;

    float* mb    = (float*)(ws);                   //   401,408 B
    float* rb    = (float*)(ws +   401408L);       //   401,408 B
    short* qkvP  = (short*)(ws +   802816L);       //   221,184 B
    short* projP = (short*)(ws +  1024000L);       //    73,728 B
    short* fc1P  = (short*)(ws +  1097728L);       //   294,912 B
    short* fc2P  = (short*)(ws +  1392640L);       //   294,912 B
    float* bmT   = (float*)(ws +  1687552L);       //   230,496 B  (~1.92 MB total)

    pack_k<192, 576><<<432, 256, 0, stream>>>(qkv_w, qkvP);
    pack_proj_k<<<144, 256, 0, stream>>>(proj_w, projP);
    pack_k<192, 768><<<576, 256, 0, stream>>>(fc1_w, fc1P);
    pack_fc2_k<<<576, 256, 0, stream>>>(fc2_w, fc2P);
    biasprep_k<<<226, 256, 0, stream>>>(relb, bmT);

    // 1) LN1 stats
    lnstats_k<<<T / 4, 256, 0, stream>>>(x, mb, rb);
    // 2) fused LN1+shift+window+QKV+MFMA attention -> d_out (natural order)
    winattn_k<<<2048, 256, 0, stream>>>(x, n1g, n1b, qkvP, qkv_b,
                                        bmT, mb, rb, out);
    // 3) x1 = attn @ proj_w + proj_b + x   (in place on d_out)
    proj_k<<<T / 64, 256, 0, stream>>>(out, projP, proj_b, x, out);
    // 4) out = x1 + GELU(LN2(x1)@fc1+b1)@fc2 + b2   (in place, LN2 fused)
    mlp_k<<<T / 64, 256, 0, stream>>>(out, n2g, n2b, fc1P, fc1_b,
                                      fc2P, fc2_b, out);
}